// Round 11
// baseline (3592.559 us; speedup 1.0000x reference)
//
#include <hip/hip_runtime.h>

#define TSTEPS 784
#define BATCH  128
#define HID    256
#define WPG    8     // workgroups per group
#define BG     4     // batches per group
#define NSET   16    // WG-sets; each set = 8 WGs serving 2 groups (8 batches)
#define COLS   32    // hidden cols owned per WG
#define RLOC   128   // local gate rows per WG (4 gates x 32 cols)
typedef unsigned long long u64;
typedef float v4f __attribute__((ext_vector_type(4)));
typedef float v2f __attribute__((ext_vector_type(2)));

// ---------------- prep: permute input (x transposed to [b][t]) ----------------
__global__ void prep_x(const float* __restrict__ in, const int* __restrict__ perm,
                       float* __restrict__ xp) {
    int b = blockIdx.x;
    for (int t = threadIdx.x; t < TSTEPS; t += blockDim.x)
        xp[b * TSTEPS + t] = in[b * TSTEPS + perm[t]];
}

// slots[parity][b][k]: hi32 = tag, lo32 = f32 bits. parity0: tag0/val0 = 0ull.
__global__ void prep_slots(u64* __restrict__ slots) {
    int i = blockIdx.x * blockDim.x + threadIdx.x;
    if (i < BATCH * HID)          slots[i] = 0ull;
    else if (i < 2 * BATCH * HID) slots[i] = 0xFFFFFFFF00000000ull;
}

// packed 2-wide f32 fma: acc += a*b
#define PK_FMA(acc, a, b) \
    asm("v_pk_fma_f32 %0, %1, %2, %0" : "+v"(acc) : "v"(a), "v"(b))

// ---------------- main persistent LSTM kernel ----------------
// grid 128 x 1024. set = blockIdx&15 owns batches [8*set, 8*set+8) as TWO
// groups: A = [8set,8set+4), B = [8set+4,8set+8). The 8 WGs of a set
// (blockIdx = set + 16*wgi) each own cols [32wgi,32wgi+32) and alternate
// A-phase / B-phase each timestep, so A's store->visible latency hides under
// B's compute and vice versa (exchange legs off the critical path).
// Exchange: r4-proven tagged u64 agent-atomic slots (the ONLY reliably
// timely path on gfx950 — r6 deadlock, r7/r10 nulls).
// Dot: r = tid>>3 local gate-row (gate=r>>5, col=r&31), s = tid&7 k-slice of
// 32; 32 weights/thread rotate-stored (conflict-free broadcast ds_read_b128),
// v_pk_fma_f32. Weights FORCE-pinned in VGPRs by an in-loop keep-alive asm
// (loop-carried liveness; one-shot pin provably failed: VGPR_Count 36-44).
__global__ __launch_bounds__(1024, 4) void lstm_kernel(
    const float* __restrict__ Whh, const float* __restrict__ Wih,
    const float* __restrict__ bih, const float* __restrict__ bhh,
    const float* __restrict__ xp, u64* __restrict__ slots)
{
    __shared__ float h_A[BG * HID];              // 4 KB staged h_t, group A
    __shared__ float h_B[BG * HID];              // 4 KB staged h_t, group B
    __shared__ float gate_lds[BG * 132];         // shared A/B (phases disjoint)
    __shared__ float x_lds[2 * BG * TSTEPS];     // 24.5 KB, 8 batches
    __shared__ float c_A[BG * COLS];
    __shared__ float c_B[BG * COLS];
    __shared__ float bias_lds[RLOC];
    __shared__ float win_lds[RLOC];

    const int tid = threadIdx.x;
    const int set     = blockIdx.x & 15;
    const int wgi     = blockIdx.x >> 4;
    const int B0A     = set * 8;
    const int B0B     = set * 8 + 4;
    const int colbase = wgi * COLS;

    const int r = tid >> 3;                  // local gate-row 0..127
    const int s = tid & 7;                   // k-slice
    const int gate = r >> 5;                 // wave-uniform
    const int R = gate * 256 + colbase + (r & 31);   // global gate row

    // ---- one-time loads; rotate-store: reg d holds quad index (d+s)&7 ----
    v4f w0, w1, w2, w3, w4, w5, w6, w7;
    {
        const v4f* wp = (const v4f*)(Whh + R * HID + s * 32);
        w0 = wp[(0 + s) & 7]; w1 = wp[(1 + s) & 7];
        w2 = wp[(2 + s) & 7]; w3 = wp[(3 + s) & 7];
        w4 = wp[(4 + s) & 7]; w5 = wp[(5 + s) & 7];
        w6 = wp[(6 + s) & 7]; w7 = wp[(7 + s) & 7];
    }

    if (tid < RLOC) {
        int gr = (tid >> 5) * 256 + colbase + (tid & 31);
        bias_lds[tid] = bih[gr] + bhh[gr];
        win_lds[tid]  = Wih[gr];
    }
    #pragma unroll
    for (int b = 0; b < 2 * BG; ++b)
        if (tid < TSTEPS) x_lds[b * TSTEPS + tid] = xp[(B0A + b) * TSTEPS + tid];
    if (tid < BG * COLS) { c_A[tid] = 0.f; c_B[tid] = 0.f; }
    __syncthreads();

    // poll targets: thread stages element (pb, pk) for each group
    const int pb = tid >> 8, pk = tid & 255;
    u64* const slotA0 = slots + (B0A + pb) * HID + pk;
    u64* const slotA1 = slots + BATCH * HID + (B0A + pb) * HID + pk;
    u64* const slotB0 = slots + (B0B + pb) * HID + pk;
    u64* const slotB1 = slots + BATCH * HID + (B0B + pb) * HID + pk;

    // ---- the pk_fma dot over one staged h buffer (a0..a3 live at macro end) --
    #define DO_DOT(HSRC)                                                      \
        v2f acc0 = {0.f, 0.f}, acc1 = {0.f, 0.f},                             \
            acc2 = {0.f, 0.f}, acc3 = {0.f, 0.f};                             \
        {                                                                     \
            const float* hbase = (HSRC) + s * 32;                             \
            DOT_STEP(0, w0) DOT_STEP(1, w1) DOT_STEP(2, w2) DOT_STEP(3, w3)   \
            DOT_STEP(4, w4) DOT_STEP(5, w5) DOT_STEP(6, w6) DOT_STEP(7, w7)   \
        }                                                                     \
        float a0 = acc0.x + acc0.y;                                           \
        float a1 = acc1.x + acc1.y;                                           \
        float a2 = acc2.x + acc2.y;                                           \
        float a3 = acc3.x + acc3.y;                                           \
        _Pragma("unroll")                                                     \
        for (int m = 1; m < 8; m <<= 1) {                                     \
            a0 += __shfl_xor(a0, m, 64);                                      \
            a1 += __shfl_xor(a1, m, 64);                                      \
            a2 += __shfl_xor(a2, m, 64);                                      \
            a3 += __shfl_xor(a3, m, 64);                                      \
        }

    #define DOT_STEP(d, wd)                                                   \
    {                                                                         \
        int off = (((d) + s) & 7) * 4;                                        \
        v4f hq0 = *(const v4f*)(hbase + off);                                 \
        v4f hq1 = *(const v4f*)(hbase + 256 + off);                           \
        v4f hq2 = *(const v4f*)(hbase + 512 + off);                           \
        v4f hq3 = *(const v4f*)(hbase + 768 + off);                           \
        v2f wlo = __builtin_shufflevector(wd, wd, 0, 1);                      \
        v2f whi = __builtin_shufflevector(wd, wd, 2, 3);                      \
        PK_FMA(acc0, wlo, __builtin_shufflevector(hq0, hq0, 0, 1));           \
        PK_FMA(acc0, whi, __builtin_shufflevector(hq0, hq0, 2, 3));           \
        PK_FMA(acc1, wlo, __builtin_shufflevector(hq1, hq1, 0, 1));           \
        PK_FMA(acc1, whi, __builtin_shufflevector(hq1, hq1, 2, 3));           \
        PK_FMA(acc2, wlo, __builtin_shufflevector(hq2, hq2, 0, 1));           \
        PK_FMA(acc2, whi, __builtin_shufflevector(hq2, hq2, 2, 3));           \
        PK_FMA(acc3, wlo, __builtin_shufflevector(hq3, hq3, 0, 1));           \
        PK_FMA(acc3, whi, __builtin_shufflevector(hq3, hq3, 2, 3));           \
    }

    for (int t = 0; t < TSTEPS; ++t) {
        // FORCE weights to stay register-resident: loop-carried asm redefine.
        asm volatile("" : "+v"(w0), "+v"(w1), "+v"(w2), "+v"(w3),
                          "+v"(w4), "+v"(w5), "+v"(w6), "+v"(w7));

        // ================= GROUP A phase =================
        {
            u64* sp = (t & 1) ? slotA1 : slotA0;
            u64 v;
            do { v = __hip_atomic_load(sp, __ATOMIC_RELAXED, __HIP_MEMORY_SCOPE_AGENT);
            } while ((unsigned)(v >> 32) != (unsigned)t);
            h_A[tid] = __uint_as_float((unsigned)v);
        }
        __syncthreads();
        {
            DO_DOT(h_A)
            if (s < BG) {
                float sum = (s == 0) ? a0 : (s == 1) ? a1 : (s == 2) ? a2 : a3;
                float xv = x_lds[s * TSTEPS + t];
                float full = fmaf(win_lds[r], xv, sum + bias_lds[r]);
                float pre = (gate == 2) ? 2.f * full : full;   // tanh = 2sig(2x)-1
                float rec = 1.f / (1.f + __expf(-pre));
                float act = (gate == 2) ? fmaf(2.f, rec, -1.f) : rec;
                gate_lds[s * 132 + r] = act;
            }
        }
        __syncthreads();
        if (tid < BG * COLS) {
            int b = tid >> 5, j = tid & 31;
            float iv = gate_lds[b * 132 + j];
            float fv = gate_lds[b * 132 + 32 + j];
            float gv = gate_lds[b * 132 + 64 + j];
            float ov = gate_lds[b * 132 + 96 + j];
            float cn = fmaf(fv, c_A[tid], iv * gv);
            c_A[tid] = cn;
            float tc = 2.f / (1.f + __expf(-2.f * cn)) - 1.f;
            float hn = ov * tc;
            u64 val = ((u64)(unsigned)(t + 1) << 32) | (u64)__float_as_uint(hn);
            u64* dp = slots + ((t + 1) & 1) * (BATCH * HID)
                            + (B0A + b) * HID + colbase + j;
            __hip_atomic_store(dp, val, __ATOMIC_RELAXED, __HIP_MEMORY_SCOPE_AGENT);
        }
        // (no barrier: updater threads proceed in program order; stageB memory
        //  is disjoint from gate_lds; actB writes gate_lds only after the
        //  post-stageB barrier, which updaters reach after finishing updA.)

        // ================= GROUP B phase =================
        // A's stores fly to the LLC underneath this whole phase.
        {
            u64* sp = (t & 1) ? slotB1 : slotB0;
            u64 v;
            do { v = __hip_atomic_load(sp, __ATOMIC_RELAXED, __HIP_MEMORY_SCOPE_AGENT);
            } while ((unsigned)(v >> 32) != (unsigned)t);
            h_B[tid] = __uint_as_float((unsigned)v);
        }
        __syncthreads();
        {
            DO_DOT(h_B)
            if (s < BG) {
                float sum = (s == 0) ? a0 : (s == 1) ? a1 : (s == 2) ? a2 : a3;
                float xv = x_lds[(BG + s) * TSTEPS + t];
                float full = fmaf(win_lds[r], xv, sum + bias_lds[r]);
                float pre = (gate == 2) ? 2.f * full : full;
                float rec = 1.f / (1.f + __expf(-pre));
                float act = (gate == 2) ? fmaf(2.f, rec, -1.f) : rec;
                gate_lds[s * 132 + r] = act;
            }
        }
        __syncthreads();
        if (tid < BG * COLS) {
            int b = tid >> 5, j = tid & 31;
            float iv = gate_lds[b * 132 + j];
            float fv = gate_lds[b * 132 + 32 + j];
            float gv = gate_lds[b * 132 + 64 + j];
            float ov = gate_lds[b * 132 + 96 + j];
            float cn = fmaf(fv, c_B[tid], iv * gv);
            c_B[tid] = cn;
            float tc = 2.f / (1.f + __expf(-2.f * cn)) - 1.f;
            float hn = ov * tc;
            u64 val = ((u64)(unsigned)(t + 1) << 32) | (u64)__float_as_uint(hn);
            u64* dp = slots + ((t + 1) & 1) * (BATCH * HID)
                            + (B0B + b) * HID + colbase + j;
            __hip_atomic_store(dp, val, __ATOMIC_RELAXED, __HIP_MEMORY_SCOPE_AGENT);
        }
        // same disjointness argument for looping back to stageA(t+1).
    }
    #undef DOT_STEP
    #undef DO_DOT
}

// ---------------- final linear: out = h_784 @ lin_W.T + lin_b ----------------
__global__ void out_kernel(const u64* __restrict__ slots, const float* __restrict__ linW,
                           const float* __restrict__ linb, float* __restrict__ out) {
    __shared__ float hl[HID];
    int b = blockIdx.x;
    // T=784 even -> final h is in parity-0 slots, low 32 bits
    for (int k = threadIdx.x; k < HID; k += blockDim.x)
        hl[k] = __uint_as_float((unsigned)slots[b * HID + k]);
    __syncthreads();
    if (threadIdx.x < 10) {
        int n = threadIdx.x;
        float acc = linb[n];
        for (int k = 0; k < HID; ++k) acc = fmaf(hl[k], linW[n * HID + k], acc);
        out[b * 10 + n] = acc;
    }
}

extern "C" void kernel_launch(void* const* d_in, const int* in_sizes, int n_in,
                              void* d_out, int out_size, void* d_ws, size_t ws_size,
                              hipStream_t stream) {
    const float* inputs = (const float*)d_in[0];
    const int*   perm   = (const int*)d_in[1];
    const float* Wih    = (const float*)d_in[2];
    const float* Whh    = (const float*)d_in[3];
    const float* bih    = (const float*)d_in[4];
    const float* bhh    = (const float*)d_in[5];
    const float* linW   = (const float*)d_in[6];
    const float* linb   = (const float*)d_in[7];
    float* out = (float*)d_out;

    // d_ws layout: slots[2][128][256] u64 (512KB) | xp[128][784] f32 (401KB)
    u64*   slots = (u64*)d_ws;
    float* xp    = (float*)(slots + 2 * BATCH * HID);

    prep_x<<<BATCH, 256, 0, stream>>>(inputs, perm, xp);
    prep_slots<<<(2 * BATCH * HID + 255) / 256, 256, 0, stream>>>(slots);
    lstm_kernel<<<NSET * WPG, 1024, 0, stream>>>(Whh, Wih, bih, bhh, xp, slots);
    out_kernel<<<BATCH, 64, 0, stream>>>(slots, linW, linb, out);
}

// Round 13
// 3337.434 us; speedup vs baseline: 1.0764x; 1.0764x over previous
//
#include <hip/hip_runtime.h>

#define TSTEPS 784
#define BATCH  128
#define HID    256
#define WPG    8     // workgroups per group
#define BG     4     // batches per group
#define NGRP   (BATCH / BG)          // 32 groups
#define COLS   32    // hidden cols owned per WG
#define KSTR   68    // LDS h layout: word = ks*68 + b*16 + kj (16B-aligned)
#define HBUF   (16 * KSTR)           // 1088 words per parity buffer
typedef unsigned long long u64;
typedef float v4f __attribute__((ext_vector_type(4)));
typedef float v2f __attribute__((ext_vector_type(2)));

// ---------------- prep: permute input (x transposed to [b][t]) ----------------
__global__ void prep_x(const float* __restrict__ in, const int* __restrict__ perm,
                       float* __restrict__ xp) {
    int b = blockIdx.x;
    for (int t = threadIdx.x; t < TSTEPS; t += blockDim.x)
        xp[b * TSTEPS + t] = in[b * TSTEPS + perm[t]];
}

// slots[parity][b][k]: hi32 = tag, lo32 = f32 bits. parity0: tag0/val0 = 0ull.
__global__ void prep_slots(u64* __restrict__ slots) {
    int i = blockIdx.x * blockDim.x + threadIdx.x;
    if (i < BATCH * HID)          slots[i] = 0ull;
    else if (i < 2 * BATCH * HID) slots[i] = 0xFFFFFFFF00000000ull;
}

// packed 2-wide f32 fma: acc += a*b
#define PK_FMA(acc, a, b) \
    asm("v_pk_fma_f32 %0, %1, %2, %0" : "+v"(acc) : "v"(a), "v"(b))
// DPP-fused butterfly add: x += dpp(x) (r5-proven pattern)
#define DPP_ADD(x, ctl) asm("v_add_f32 %0, %1, %0 " ctl " row_mask:0xf bank_mask:0xf" \
                            : "+v"(x) : "v"(x))
#define LO2(V) __builtin_shufflevector(V, V, 0, 1)
#define HI2(V) __builtin_shufflevector(V, V, 2, 3)

// ---------------- main persistent LSTM kernel ----------------
// grid 256 x 1024. group g = blockIdx&31 owns batches [4g,4g+4).
// WG wgi = blockIdx>>5 owns cols [32wgi,32wgi+32).
// Thread = (col = tid>>5, bp = (tid>>4)&1, ks = tid&15): owns ALL 4 gates of
// its column for k in [16ks,16ks+16) (64 weights in 16 v4f) and batches
// {2bp, 2bp+1}. Coverage per (col,bp): 16 lanes x 16 k = 256 ✓ (fixes r12's
// 4x-short bug). Lane = (col&1)*32 + bp*16 + ks, so each 16-lane DPP row is
// one (col,bp): k-reduce = 4 DPP stages (VALU; zero DS-pipe, unlike shfl).
// LDS h reads: 8 ds_read_b128/thread (128/WG, 4x fewer than r4) from the
// k-subtiled layout word = ks*KSTR + b*16 + kj. Epilogue in-lane (c in VGPRs,
// bit-identical across the row by commutativity); lane ks==0 publishes via
// the r4-proven tagged agent-atomic slots. Single barrier/step (r12 scheme;
// safety: dot(t) precedes barrier(t+1) precedes stage(t+2) in program order,
// and a visible tag t implies its producer WG passed barrier(t-1)).
__global__ __launch_bounds__(1024, 4) void lstm_kernel(
    const float* __restrict__ Whh, const float* __restrict__ Wih,
    const float* __restrict__ bih, const float* __restrict__ bhh,
    const float* __restrict__ xp, u64* __restrict__ slots)
{
    __shared__ float h_lds[2][HBUF];             // 8.7 KB double-buffered h_t
    __shared__ float x_lds[BG * TSTEPS];         // 12.25 KB
    __shared__ v4f   bias4[COLS];                // {i,f,g,o} per col
    __shared__ v4f   win4[COLS];

    const int tid = threadIdx.x;
    const int g       = blockIdx.x & 31;
    const int wgi     = blockIdx.x >> 5;
    const int B0      = g * BG;
    const int colbase = wgi * COLS;

    const int ks  = tid & 15;         // k-slice: k in [16ks, 16ks+16)
    const int bp  = (tid >> 4) & 1;   // batch pair: batches {2bp, 2bp+1}
    const int col = tid >> 5;         // local col 0..31

    // ---- one-time: 64 weights (4 gates x 16 k) in 16 v4f ----
    v4f w[4][4];
    #pragma unroll
    for (int q = 0; q < 4; ++q) {
        const v4f* wp = (const v4f*)(Whh + (q * 256 + colbase + col) * HID + 16 * ks);
        w[q][0] = wp[0]; w[q][1] = wp[1]; w[q][2] = wp[2]; w[q][3] = wp[3];
    }
    if (tid < COLS) {
        v4f b4, w4_;
        #pragma unroll
        for (int q = 0; q < 4; ++q) {
            int R = q * 256 + colbase + tid;
            b4[q] = bih[R] + bhh[R];
            w4_[q] = Wih[R];
        }
        bias4[tid] = b4; win4[tid] = w4_;
    }
    #pragma unroll
    for (int bb = 0; bb < BG; ++bb)
        if (tid < TSTEPS) x_lds[bb * TSTEPS + tid] = xp[(B0 + bb) * TSTEPS + tid];
    __syncthreads();

    // staging identity: thread polls slot (pb, pk) of the group's h
    const int pb = tid >> 8, pk = tid & 255;
    u64* const slot0 = slots + (B0 + pb) * HID + pk;               // parity 0
    u64* const slot1 = slots + BATCH * HID + (B0 + pb) * HID + pk; // parity 1
    const int hidx = (pk >> 4) * KSTR + pb * 16 + (pk & 15);

    float c0 = 0.f, c1 = 0.f;   // c for batches 2bp, 2bp+1 (replicated in row)

    for (int t = 0; t < TSTEPS; ++t) {
        const int cur = t & 1;
        // keep weights register-resident across the loop
        #pragma unroll
        for (int q = 0; q < 4; ++q)
            asm volatile("" : "+v"(w[q][0]), "+v"(w[q][1]), "+v"(w[q][2]), "+v"(w[q][3]));

        // ---- stage h_t: poll tagged slot (r4-proven), write subtiled LDS ----
        {
            u64* sp = cur ? slot1 : slot0;
            u64 v;
            do { v = __hip_atomic_load(sp, __ATOMIC_RELAXED, __HIP_MEMORY_SCOPE_AGENT);
            } while ((unsigned)(v >> 32) != (unsigned)t);
            h_lds[cur][hidx] = __uint_as_float((unsigned)v);
        }
        __syncthreads();

        // ---- dot: 8x ds_read_b128, 64 pk_fma ----
        const float* hb = &h_lds[cur][ks * KSTR + bp * 32];
        v2f a00 = {0.f,0.f}, a10 = {0.f,0.f}, a20 = {0.f,0.f}, a30 = {0.f,0.f};
        v2f a01 = {0.f,0.f}, a11 = {0.f,0.f}, a21 = {0.f,0.f}, a31 = {0.f,0.f};
        {   // batch 2bp
            v4f hc0 = *(const v4f*)(hb + 0);
            v4f hc1 = *(const v4f*)(hb + 4);
            v4f hc2 = *(const v4f*)(hb + 8);
            v4f hc3 = *(const v4f*)(hb + 12);
            PK_FMA(a00, LO2(w[0][0]), LO2(hc0)); PK_FMA(a00, HI2(w[0][0]), HI2(hc0));
            PK_FMA(a00, LO2(w[0][1]), LO2(hc1)); PK_FMA(a00, HI2(w[0][1]), HI2(hc1));
            PK_FMA(a00, LO2(w[0][2]), LO2(hc2)); PK_FMA(a00, HI2(w[0][2]), HI2(hc2));
            PK_FMA(a00, LO2(w[0][3]), LO2(hc3)); PK_FMA(a00, HI2(w[0][3]), HI2(hc3));
            PK_FMA(a10, LO2(w[1][0]), LO2(hc0)); PK_FMA(a10, HI2(w[1][0]), HI2(hc0));
            PK_FMA(a10, LO2(w[1][1]), LO2(hc1)); PK_FMA(a10, HI2(w[1][1]), HI2(hc1));
            PK_FMA(a10, LO2(w[1][2]), LO2(hc2)); PK_FMA(a10, HI2(w[1][2]), HI2(hc2));
            PK_FMA(a10, LO2(w[1][3]), LO2(hc3)); PK_FMA(a10, HI2(w[1][3]), HI2(hc3));
            PK_FMA(a20, LO2(w[2][0]), LO2(hc0)); PK_FMA(a20, HI2(w[2][0]), HI2(hc0));
            PK_FMA(a20, LO2(w[2][1]), LO2(hc1)); PK_FMA(a20, HI2(w[2][1]), HI2(hc1));
            PK_FMA(a20, LO2(w[2][2]), LO2(hc2)); PK_FMA(a20, HI2(w[2][2]), HI2(hc2));
            PK_FMA(a20, LO2(w[2][3]), LO2(hc3)); PK_FMA(a20, HI2(w[2][3]), HI2(hc3));
            PK_FMA(a30, LO2(w[3][0]), LO2(hc0)); PK_FMA(a30, HI2(w[3][0]), HI2(hc0));
            PK_FMA(a30, LO2(w[3][1]), LO2(hc1)); PK_FMA(a30, HI2(w[3][1]), HI2(hc1));
            PK_FMA(a30, LO2(w[3][2]), LO2(hc2)); PK_FMA(a30, HI2(w[3][2]), HI2(hc2));
            PK_FMA(a30, LO2(w[3][3]), LO2(hc3)); PK_FMA(a30, HI2(w[3][3]), HI2(hc3));
        }
        {   // batch 2bp+1
            v4f hc0 = *(const v4f*)(hb + 16);
            v4f hc1 = *(const v4f*)(hb + 20);
            v4f hc2 = *(const v4f*)(hb + 24);
            v4f hc3 = *(const v4f*)(hb + 28);
            PK_FMA(a01, LO2(w[0][0]), LO2(hc0)); PK_FMA(a01, HI2(w[0][0]), HI2(hc0));
            PK_FMA(a01, LO2(w[0][1]), LO2(hc1)); PK_FMA(a01, HI2(w[0][1]), HI2(hc1));
            PK_FMA(a01, LO2(w[0][2]), LO2(hc2)); PK_FMA(a01, HI2(w[0][2]), HI2(hc2));
            PK_FMA(a01, LO2(w[0][3]), LO2(hc3)); PK_FMA(a01, HI2(w[0][3]), HI2(hc3));
            PK_FMA(a11, LO2(w[1][0]), LO2(hc0)); PK_FMA(a11, HI2(w[1][0]), HI2(hc0));
            PK_FMA(a11, LO2(w[1][1]), LO2(hc1)); PK_FMA(a11, HI2(w[1][1]), HI2(hc1));
            PK_FMA(a11, LO2(w[1][2]), LO2(hc2)); PK_FMA(a11, HI2(w[1][2]), HI2(hc2));
            PK_FMA(a11, LO2(w[1][3]), LO2(hc3)); PK_FMA(a11, HI2(w[1][3]), HI2(hc3));
            PK_FMA(a21, LO2(w[2][0]), LO2(hc0)); PK_FMA(a21, HI2(w[2][0]), HI2(hc0));
            PK_FMA(a21, LO2(w[2][1]), LO2(hc1)); PK_FMA(a21, HI2(w[2][1]), HI2(hc1));
            PK_FMA(a21, LO2(w[2][2]), LO2(hc2)); PK_FMA(a21, HI2(w[2][2]), HI2(hc2));
            PK_FMA(a21, LO2(w[2][3]), LO2(hc3)); PK_FMA(a21, HI2(w[2][3]), HI2(hc3));
            PK_FMA(a31, LO2(w[3][0]), LO2(hc0)); PK_FMA(a31, HI2(w[3][0]), HI2(hc0));
            PK_FMA(a31, LO2(w[3][1]), LO2(hc1)); PK_FMA(a31, HI2(w[3][1]), HI2(hc1));
            PK_FMA(a31, LO2(w[3][2]), LO2(hc2)); PK_FMA(a31, HI2(w[3][2]), HI2(hc2));
            PK_FMA(a31, LO2(w[3][3]), LO2(hc3)); PK_FMA(a31, HI2(w[3][3]), HI2(hc3));
        }
        float s00 = a00.x + a00.y, s10 = a10.x + a10.y;
        float s20 = a20.x + a20.y, s30 = a30.x + a30.y;
        float s01 = a01.x + a01.y, s11 = a11.x + a11.y;
        float s21 = a21.x + a21.y, s31 = a31.x + a31.y;

        // ---- k-reduce within the 16-lane DPP row (all-VALU, no DS pipe).
        //      After 4 stages every lane holds the full 256-k sum. ----
        #define RSTAGE(ctl) \
            DPP_ADD(s00, ctl); DPP_ADD(s10, ctl); DPP_ADD(s20, ctl); DPP_ADD(s30, ctl); \
            DPP_ADD(s01, ctl); DPP_ADD(s11, ctl); DPP_ADD(s21, ctl); DPP_ADD(s31, ctl);
        RSTAGE("quad_perm:[1,0,3,2]")
        RSTAGE("quad_perm:[2,3,0,1]")
        RSTAGE("row_half_mirror")
        RSTAGE("row_mirror")
        #undef RSTAGE

        // ---- in-lane epilogue: both batches (replicated across row, exact) ----
        v4f b4 = bias4[col];
        v4f wn = win4[col];
        {
            float xv = x_lds[(2 * bp) * TSTEPS + t];
            float p0 = fmaf(wn.x, xv, s00 + b4.x);
            float p1 = fmaf(wn.y, xv, s10 + b4.y);
            float p2 = fmaf(wn.z, xv, s20 + b4.z);
            float p3 = fmaf(wn.w, xv, s30 + b4.w);
            float iv = 1.f / (1.f + __expf(-p0));
            float fv = 1.f / (1.f + __expf(-p1));
            float gv = 2.f / (1.f + __expf(-2.f * p2)) - 1.f;
            float ov = 1.f / (1.f + __expf(-p3));
            c0 = fmaf(fv, c0, iv * gv);
            float th = 2.f / (1.f + __expf(-2.f * c0)) - 1.f;
            float hn = ov * th;
            if (ks == 0) {
                u64 val = ((u64)(unsigned)(t + 1) << 32) | (u64)__float_as_uint(hn);
                u64* dp = slots + ((t + 1) & 1) * (BATCH * HID)
                                + (B0 + 2 * bp) * HID + colbase + col;
                __hip_atomic_store(dp, val, __ATOMIC_RELAXED, __HIP_MEMORY_SCOPE_AGENT);
            }
        }
        {
            float xv = x_lds[(2 * bp + 1) * TSTEPS + t];
            float p0 = fmaf(wn.x, xv, s01 + b4.x);
            float p1 = fmaf(wn.y, xv, s11 + b4.y);
            float p2 = fmaf(wn.z, xv, s21 + b4.z);
            float p3 = fmaf(wn.w, xv, s31 + b4.w);
            float iv = 1.f / (1.f + __expf(-p0));
            float fv = 1.f / (1.f + __expf(-p1));
            float gv = 2.f / (1.f + __expf(-2.f * p2)) - 1.f;
            float ov = 1.f / (1.f + __expf(-p3));
            c1 = fmaf(fv, c1, iv * gv);
            float th = 2.f / (1.f + __expf(-2.f * c1)) - 1.f;
            float hn = ov * th;
            if (ks == 0) {
                u64 val = ((u64)(unsigned)(t + 1) << 32) | (u64)__float_as_uint(hn);
                u64* dp = slots + ((t + 1) & 1) * (BATCH * HID)
                                + (B0 + 2 * bp + 1) * HID + colbase + col;
                __hip_atomic_store(dp, val, __ATOMIC_RELAXED, __HIP_MEMORY_SCOPE_AGENT);
            }
        }
        // single barrier/step: stage(t+1) targets buf[(t+1)&1] (disjoint from
        // any straggler's dot(t) reads of buf[t&1]); see header comment.
    }
}

// ---------------- final linear: out = h_784 @ lin_W.T + lin_b ----------------
__global__ void out_kernel(const u64* __restrict__ slots, const float* __restrict__ linW,
                           const float* __restrict__ linb, float* __restrict__ out) {
    __shared__ float hl[HID];
    int b = blockIdx.x;
    // T=784 even -> final h is in parity-0 slots, low 32 bits
    for (int k = threadIdx.x; k < HID; k += blockDim.x)
        hl[k] = __uint_as_float((unsigned)slots[b * HID + k]);
    __syncthreads();
    if (threadIdx.x < 10) {
        int n = threadIdx.x;
        float acc = linb[n];
        for (int k = 0; k < HID; ++k) acc = fmaf(hl[k], linW[n * HID + k], acc);
        out[b * 10 + n] = acc;
    }
}

extern "C" void kernel_launch(void* const* d_in, const int* in_sizes, int n_in,
                              void* d_out, int out_size, void* d_ws, size_t ws_size,
                              hipStream_t stream) {
    const float* inputs = (const float*)d_in[0];
    const int*   perm   = (const int*)d_in[1];
    const float* Wih    = (const float*)d_in[2];
    const float* Whh    = (const float*)d_in[3];
    const float* bih    = (const float*)d_in[4];
    const float* bhh    = (const float*)d_in[5];
    const float* linW   = (const float*)d_in[6];
    const float* linb   = (const float*)d_in[7];
    float* out = (float*)d_out;

    // d_ws layout: slots[2][128][256] u64 (512KB) | xp[128][784] f32 (401KB)
    u64*   slots = (u64*)d_ws;
    float* xp    = (float*)(slots + 2 * BATCH * HID);

    prep_x<<<BATCH, 256, 0, stream>>>(inputs, perm, xp);
    prep_slots<<<(2 * BATCH * HID + 255) / 256, 256, 0, stream>>>(slots);
    lstm_kernel<<<NGRP * WPG, 1024, 0, stream>>>(Whh, Wih, bih, bhh, xp, slots);
    out_kernel<<<BATCH, 64, 0, stream>>>(slots, linW, linb, out);
}